// Round 8
// baseline (904.879 us; speedup 1.0000x reference)
//
#include <hip/hip_runtime.h>
#include <stdint.h>
#include <stddef.h>

typedef float f32x16 __attribute__((ext_vector_type(16)));
typedef int i32x8 __attribute__((ext_vector_type(8)));

union Frag32 { long l[4]; i32x8 v; };  // 32 bytes = one scaled-MFMA operand/lane

// ---------------------------------------------------------------------------
// Quantized operands live in an "LDS-image" layout: 8 KB slots; slot
// s = blk*(K/32) + ksl holds rows [blk*256..+256) x k-bytes [ksl*32..+32).
// Swizzle (16B granular): logical L = row*32 + kkb stored at physical
// P = L ^ (((row>>2)&1)<<4)  — the two 16B chunks of a row swap when
// row bit2 is set.  GEMM stages 16 KB slices (2 slots) with a LINEAR
// contiguous copy (global_load_lds x16); fragment reads are ds_read_b128 at
// P = h*8192 + row*32 + ((c ^ ((row>>2)&1))<<4): rows stride 8 banks and the
// XOR alternates the halves -> exactly 8 accesses/bank = the b128 floor,
// zero conflicts. (8B-chunk variant verified 0 conflicts R3-R6; same
// bijectivity argument, b128 issue rate 12cy/inst vs b64 8cy/inst.)
//
// GEMM inner op: mfma_scale_f32_32x32x64_f8f6f4 with unit E8M0 scales
// (0x7F/byte -> x1.0): bit-exact fp8 matmul at the 2x MX rate.
//
// Workspace layout (bytes):
//   [0..7]    : two u32 atomic absmax slots (w_absmax_bits, x_absmax_bits)
//   [256 .. 256+M*K)            : x_q  LDS-image slots (32 MB)
//   [256+M*K .. 256+M*K+N*K)    : w_qT LDS-image slots (64 MB)
// ---------------------------------------------------------------------------

__global__ void absmax_kernel(const float4* __restrict__ x, size_t n4,
                              unsigned int* __restrict__ out) {
  size_t idx = ((size_t)blockIdx.x * blockDim.x + threadIdx.x) * 2;
  size_t stride = (size_t)gridDim.x * blockDim.x * 2;
  float m0 = 0.f, m1 = 0.f;
  for (size_t i = idx; i < n4; i += stride) {
    float4 v = x[i];
    float4 u = x[i + 1];  // n4 is even for both inputs
    m0 = fmaxf(m0, fmaxf(fmaxf(fabsf(v.x), fabsf(v.y)),
                         fmaxf(fabsf(v.z), fabsf(v.w))));
    m1 = fmaxf(m1, fmaxf(fmaxf(fabsf(u.x), fabsf(u.y)),
                         fmaxf(fabsf(u.z), fabsf(u.w))));
  }
  float m = fmaxf(m0, m1);
#pragma unroll
  for (int off = 32; off > 0; off >>= 1)
    m = fmaxf(m, __shfl_xor(m, off));
  if ((threadIdx.x & 63) == 0)
    atomicMax(out, __float_as_uint(m));  // all values >= 0: uint order == float order
}

// x [M][K] f32 -> LDS-image slots. One thread = one 16B logical chunk
// (whole chunk moves as a unit under the 16B swizzle: single uint4 store).
__global__ void quantize_x_kernel(const float4* __restrict__ x,
                                  uint8_t* __restrict__ xq,
                                  const unsigned int* __restrict__ amax,
                                  int K, int n_chunks) {
  const float x_scale = __uint_as_float(amax[1]) / 448.0f;
  const float inv = 1.0f / x_scale;
  const int kslots = K >> 5;
  int idx = blockIdx.x * blockDim.x + threadIdx.x;
  const int stride = gridDim.x * blockDim.x;
  for (; idx < n_chunks; idx += stride) {
    const int slot = idx >> 9;        // 512 chunks of 16B per 8KB slot
    const int p16 = idx & 511;
    const int row = p16 >> 1;
    const int kkb0 = (p16 & 1) << 4;
    const int mblk = slot / kslots;
    const int ksl = slot - mblk * kslots;
    const size_t f4 = ((size_t)(mblk * 256 + row) * K + ksl * 32 + kkb0) >> 2;
    const float4 v0 = x[f4 + 0], v1 = x[f4 + 1], v2 = x[f4 + 2], v3 = x[f4 + 3];
    uint32_t c0 = __builtin_amdgcn_cvt_pk_fp8_f32(v0.x * inv, v0.y * inv, 0, false);
    c0 = __builtin_amdgcn_cvt_pk_fp8_f32(v0.z * inv, v0.w * inv, c0, true);
    uint32_t c1 = __builtin_amdgcn_cvt_pk_fp8_f32(v1.x * inv, v1.y * inv, 0, false);
    c1 = __builtin_amdgcn_cvt_pk_fp8_f32(v1.z * inv, v1.w * inv, c1, true);
    uint32_t c2 = __builtin_amdgcn_cvt_pk_fp8_f32(v2.x * inv, v2.y * inv, 0, false);
    c2 = __builtin_amdgcn_cvt_pk_fp8_f32(v2.z * inv, v2.w * inv, c2, true);
    uint32_t c3 = __builtin_amdgcn_cvt_pk_fp8_f32(v3.x * inv, v3.y * inv, 0, false);
    c3 = __builtin_amdgcn_cvt_pk_fp8_f32(v3.z * inv, v3.w * inv, c3, true);
    const int paddr = (row * 32 + kkb0) ^ (((row >> 2) & 1) << 4);
    uint4 o;
    o.x = c0; o.y = c1; o.z = c2; o.w = c3;
    *(uint4*)(xq + (size_t)slot * 8192 + paddr) = o;
  }
}

// w [K][N] f32 -> w^T LDS-image slots. 64n x 128k tile per block:
// f32 LDS tile [64][129], register-side 16B-chunk swap, 2x16B stores.
__global__ void quantize_wT_kernel(const float* __restrict__ w,
                                   uint8_t* __restrict__ wqt,
                                   const unsigned int* __restrict__ amax,
                                   int N, int K) {
  __shared__ float tileF[64][129];
  const float w_scale = __uint_as_float(amax[0]) / 448.0f;
  const float inv = 1.0f / w_scale;
  const int tn = blockIdx.x;   // 64-wide n tile
  const int tk = blockIdx.y;   // 128-wide k tile
  const int t = threadIdx.x;
  {
    const int nn4 = t & 15;
    const int kk0 = t >> 4;    // 0..15
#pragma unroll
    for (int i = 0; i < 8; ++i) {
      const int kk = kk0 + i * 16;  // 0..127
      const float4 v =
          *(const float4*)&w[(size_t)(tk * 128 + kk) * N + tn * 64 + nn4 * 4];
      tileF[nn4 * 4 + 0][kk] = v.x;
      tileF[nn4 * 4 + 1][kk] = v.y;
      tileF[nn4 * 4 + 2][kk] = v.z;
      tileF[nn4 * 4 + 3][kk] = v.w;
    }
  }
  __syncthreads();
  {
    const int n = t & 63;
    const int c = t >> 6;      // 0..3: which 32-k chunk (wave-uniform)
    unsigned long long q[4];
#pragma unroll
    for (int cc = 0; cc < 4; ++cc) {
      const float4 u0 = *(const float4*)&tileF[n][c * 32 + cc * 8];
      const float4 u1 = *(const float4*)&tileF[n][c * 32 + cc * 8 + 4];
      uint32_t lo = __builtin_amdgcn_cvt_pk_fp8_f32(u0.x * inv, u0.y * inv, 0, false);
      lo = __builtin_amdgcn_cvt_pk_fp8_f32(u0.z * inv, u0.w * inv, lo, true);
      uint32_t hi = __builtin_amdgcn_cvt_pk_fp8_f32(u1.x * inv, u1.y * inv, 0, false);
      hi = __builtin_amdgcn_cvt_pk_fp8_f32(u1.z * inv, u1.w * inv, hi, true);
      q[cc] = (unsigned long long)lo | ((unsigned long long)hi << 32);
    }
    const int n_g = tn * 64 + n;
    const int k0g = tk * 128 + c * 32;
    const size_t slot = (size_t)(n_g >> 8) * (K >> 5) + (k0g >> 5);
    const int row = n_g & 255;
    const int bit = (row >> 2) & 1;
    uint8_t* pbase = wqt + slot * 8192 + row * 32;
    ulonglong2 s0, s1;
    s0.x = q[0]; s0.y = q[1];   // logical chunk 0 -> physical chunk bit
    s1.x = q[2]; s1.y = q[3];   // logical chunk 1 -> physical chunk bit^1
    *(ulonglong2*)(pbase + (bit << 4)) = s0;
    *(ulonglong2*)(pbase + ((bit ^ 1) << 4)) = s1;
  }
}

// ---------------------------------------------------------------------------
// fp8 GEMM, 256x256 tile, 16 waves (4x4), 64x64/wave, 32x32x64 MX MFMA.
// 4-slice ring, lead-2 staging, counted vmcnt(2) per phase (never 0 in
// loop), b128 fragment reads, ONE barrier per TWO phases (ring-4 tolerates
// +-1 phase wave skew; see slot-liveness analysis in round notes).
// ---------------------------------------------------------------------------
#define T_BM 256
#define T_BN 256
#define UNIT_SCALE 0x7F7F7F7F

__device__ __forceinline__ void gl_lds16(const uint8_t* g, uint8_t* lds) {
  __builtin_amdgcn_global_load_lds(
      (const __attribute__((address_space(1))) void*)g,
      (__attribute__((address_space(3))) void*)lds, 16, 0, 0);
}

__global__ __launch_bounds__(1024, 4) void gemm_fp8_mx(
    const uint8_t* __restrict__ Aq, const uint8_t* __restrict__ BqT,
    const float* __restrict__ bias, const unsigned int* __restrict__ amax,
    float* __restrict__ C, int M, int N, int K) {
  extern __shared__ uint8_t smem[];
  uint8_t* const Ar = smem;            // 4 slices x 16384 = 64 KB
  uint8_t* const Br = smem + 65536;    // 4 slices x 16384 = 64 KB

  const int ntn = N / T_BN;
  const int bid = blockIdx.x;
  const int m0 = (bid / ntn) * T_BM;
  const int n0 = (bid % ntn) * T_BN;

  const int tid = threadIdx.x;
  const int w = tid >> 6;      // wave 0..15
  const int l = tid & 63;
  const int wr = w >> 2;       // 0..3  (M quarter)
  const int wc = w & 3;        // 0..3  (N quarter)

  const int kslots = K >> 5;

  // staging: linear contiguous copy of one 16 KB slice; wave w owns bytes
  // [w*1024, w*1024+1024), lane l the 16B at +l*16.
  const int soff = w * 1024 + l * 16;
  const uint8_t* a_src = Aq + (size_t)(m0 >> 8) * kslots * 8192 + soff;
  const uint8_t* b_src = BqT + (size_t)(n0 >> 8) * kslots * 8192 + soff;

  // fragment-read offsets: lane half h = l>>5 -> slot h within the slice.
  const int h = l >> 5;
  const int rl = l & 31;
  int aoff[2][2], boff[2][2];
#pragma unroll
  for (int mt = 0; mt < 2; ++mt) {
    const int ra = wr * 64 + mt * 32 + rl;
    const int rb = wc * 64 + mt * 32 + rl;
#pragma unroll
    for (int c = 0; c < 2; ++c) {
      aoff[mt][c] = h * 8192 + ra * 32 + ((c ^ ((ra >> 2) & 1)) << 4);
      boff[mt][c] = h * 8192 + rb * 32 + ((c ^ ((rb >> 2) & 1)) << 4);
    }
  }

  f32x16 acc[2][2];
#pragma unroll
  for (int i = 0; i < 2; ++i)
#pragma unroll
    for (int j = 0; j < 2; ++j) acc[i][j] = 0.f;

  const int NP = K >> 6;  // 64 phases (one 16 KB slice each), even

  // prologue: stage slices 0,1 into ring slots 0,1
  gl_lds16(a_src, Ar + soff);
  gl_lds16(b_src, Br + soff);
  gl_lds16(a_src + 16384, Ar + 16384 + soff);
  gl_lds16(b_src + 16384, Br + 16384 + soff);
  asm volatile("s_waitcnt vmcnt(2)" ::: "memory");  // slice 0 landed
  __builtin_amdgcn_s_barrier();

#define PHASE_(pp)                                                          \
  do {                                                                      \
    const int ss = ((pp) + 2 < NP) ? ((pp) + 2) : ((pp)-2);                 \
    const int rslot = (((pp) + 2) & 3) * 16384;                             \
    gl_lds16(a_src + (size_t)ss * 16384, Ar + rslot + soff);                \
    gl_lds16(b_src + (size_t)ss * 16384, Br + rslot + soff);                \
    const uint8_t* Asl = Ar + ((pp)&3) * 16384;                             \
    const uint8_t* Bsl = Br + ((pp)&3) * 16384;                             \
    Frag32 af[2], bf[2];                                                    \
    _Pragma("unroll") for (int mt = 0; mt < 2; ++mt) {                      \
      ulonglong2 ta0 = *(const ulonglong2*)(Asl + aoff[mt][0]);             \
      ulonglong2 ta1 = *(const ulonglong2*)(Asl + aoff[mt][1]);             \
      af[mt].l[0] = (long)ta0.x; af[mt].l[1] = (long)ta0.y;                 \
      af[mt].l[2] = (long)ta1.x; af[mt].l[3] = (long)ta1.y;                 \
      ulonglong2 tb0 = *(const ulonglong2*)(Bsl + boff[mt][0]);             \
      ulonglong2 tb1 = *(const ulonglong2*)(Bsl + boff[mt][1]);             \
      bf[mt].l[0] = (long)tb0.x; bf[mt].l[1] = (long)tb0.y;                 \
      bf[mt].l[2] = (long)tb1.x; bf[mt].l[3] = (long)tb1.y;                 \
    }                                                                       \
    __builtin_amdgcn_s_setprio(1);                                          \
    acc[0][0] = __builtin_amdgcn_mfma_scale_f32_32x32x64_f8f6f4(            \
        af[0].v, bf[0].v, acc[0][0], 0, 0, 0, UNIT_SCALE, 0, UNIT_SCALE);   \
    acc[1][0] = __builtin_amdgcn_mfma_scale_f32_32x32x64_f8f6f4(            \
        af[1].v, bf[0].v, acc[1][0], 0, 0, 0, UNIT_SCALE, 0, UNIT_SCALE);   \
    acc[0][1] = __builtin_amdgcn_mfma_scale_f32_32x32x64_f8f6f4(            \
        af[0].v, bf[1].v, acc[0][1], 0, 0, 0, UNIT_SCALE, 0, UNIT_SCALE);   \
    acc[1][1] = __builtin_amdgcn_mfma_scale_f32_32x32x64_f8f6f4(            \
        af[1].v, bf[1].v, acc[1][1], 0, 0, 0, UNIT_SCALE, 0, UNIT_SCALE);   \
    __builtin_amdgcn_s_setprio(0);                                          \
    asm volatile("s_waitcnt vmcnt(2)" ::: "memory");                        \
  } while (0)

  for (int p = 0; p < NP; p += 2) {
    PHASE_(p);          // no barrier mid-pair: ring-4 tolerates the skew
    PHASE_(p + 1);
    __builtin_amdgcn_s_barrier();
  }
  asm volatile("s_waitcnt vmcnt(0)" ::: "memory");  // drain tail dummies

  // epilogue: C = acc * (x_scale*w_scale) + bias
  // 32x32 C/D layout: col = l&31, row = (r&3) + 8*(r>>2) + 4*(l>>5)
  const float x_scale = __uint_as_float(amax[1]) / 448.0f;
  const float w_scale = __uint_as_float(amax[0]) / 448.0f;
  const float s = x_scale * w_scale;
  const int colb = n0 + wc * 64 + rl;
  const int rowb = m0 + wr * 64 + 4 * h;
#pragma unroll
  for (int nt = 0; nt < 2; ++nt) {
    const int col = colb + nt * 32;
    const float bv = bias[col];
#pragma unroll
    for (int mt = 0; mt < 2; ++mt) {
#pragma unroll
      for (int r = 0; r < 16; ++r) {
        const int row = rowb + mt * 32 + (r & 3) + 8 * (r >> 2);
        C[(size_t)row * N + col] = acc[mt][nt][r] * s + bv;
      }
    }
  }
}

extern "C" void kernel_launch(void* const* d_in, const int* in_sizes, int n_in,
                              void* d_out, int out_size, void* d_ws, size_t ws_size,
                              hipStream_t stream) {
  const float* inp = (const float*)d_in[0];
  const float* weight = (const float*)d_in[1];
  const float* bias = (const float*)d_in[2];
  float* out = (float*)d_out;

  const int N = in_sizes[2];                 // 16384
  const int K = in_sizes[1] / N;             // 4096
  const int M = in_sizes[0] / K;             // 8192

  uint8_t* ws = (uint8_t*)d_ws;
  unsigned int* amax = (unsigned int*)ws;
  uint8_t* xq = ws + 256;
  uint8_t* wqt = ws + 256 + (size_t)M * K;

  hipMemsetAsync(d_ws, 0, 8, stream);  // zero the two atomic absmax slots

  absmax_kernel<<<2048, 256, 0, stream>>>((const float4*)weight,
                                          (size_t)K * N / 4, amax + 0);
  absmax_kernel<<<2048, 256, 0, stream>>>((const float4*)inp,
                                          (size_t)M * K / 4, amax + 1);

  quantize_x_kernel<<<4096, 256, 0, stream>>>((const float4*)inp, xq, amax,
                                              K, M * K / 16);
  quantize_wT_kernel<<<dim3(N / 64, K / 128), 256, 0, stream>>>(weight, wqt,
                                                                amax, N, K);

  gemm_fp8_mx<<<(M / T_BM) * (N / T_BN), 1024, 131072, stream>>>(
      xq, wqt, bias, amax, out, M, N, K);
}